// Round 21
// baseline (39.922 us; speedup 1.0000x reference)
//
#include <hip/hip_runtime.h>
#include <stdint.h>

#define N_ROWS 8192
#define DIM 256

constexpr float INV_T = 1.0f / 0.07f;
constexpr float M0    = 1.0f / 0.07f;              // fixed LSE max: |cos| <= ~1
constexpr float LOG2E = 1.44269504088896f;
constexpr float C1    = INV_T * LOG2E;             // exp2-domain scale
constexpr float C0    = -M0 * LOG2E;               // exp2-domain bias
constexpr float KSCL  = 127.0f / 0.35f;            // fixed K-side int8 scale

typedef int i32x4  __attribute__((ext_vector_type(4)));
typedef int i32x16 __attribute__((ext_vector_type(16)));

__device__ inline float fast_exp2(float x) {
    float r;
    asm("v_exp_f32 %0, %1" : "=v"(r) : "v"(x));
    return r;
}
__device__ inline int pack4(int a, int b, int c, int d) {
    return (a & 0xff) | ((b & 0xff) << 8) | ((c & 0xff) << 16) | (d << 24);
}

// ---------------- Kernel 1: normalize + int8 quantize + l_pos ----------------
__global__ __launch_bounds__(256) void prep_kernel(
    const float* __restrict__ q, const float* __restrict__ k,
    int* __restrict__ qi8, int* __restrict__ ki8,
    float* __restrict__ lposT, float* __restrict__ fqs) {
    const int wid  = threadIdx.x >> 6;
    const int lane = threadIdx.x & 63;
    const int row  = blockIdx.x * 4 + wid;

    const float4 qv = *reinterpret_cast<const float4*>(q + (size_t)row * DIM + lane * 4);
    const float4 kv = *reinterpret_cast<const float4*>(k + (size_t)row * DIM + lane * 4);

    float qq = qv.x*qv.x + qv.y*qv.y + qv.z*qv.z + qv.w*qv.w;
    float kk = kv.x*kv.x + kv.y*kv.y + kv.z*kv.z + kv.w*kv.w;
    float qk = qv.x*kv.x + qv.y*kv.y + qv.z*kv.z + qv.w*kv.w;
    float qm = fmaxf(fmaxf(fabsf(qv.x), fabsf(qv.y)), fmaxf(fabsf(qv.z), fabsf(qv.w)));

    #pragma unroll
    for (int off = 32; off > 0; off >>= 1) {
        qq += __shfl_xor(qq, off, 64);
        kk += __shfl_xor(kk, off, 64);
        qk += __shfl_xor(qk, off, 64);
        qm  = fmaxf(qm, __shfl_xor(qm, off, 64));
    }
    const float iq = 1.0f / sqrtf(qq);
    const float ik = 1.0f / sqrtf(kk);

    const float ksc = ik * KSCL;
    int k0 = __float2int_rn(fminf(fmaxf(kv.x * ksc, -127.f), 127.f));
    int k1 = __float2int_rn(fminf(fmaxf(kv.y * ksc, -127.f), 127.f));
    int k2 = __float2int_rn(fminf(fmaxf(kv.z * ksc, -127.f), 127.f));
    int k3 = __float2int_rn(fminf(fmaxf(kv.w * ksc, -127.f), 127.f));
    ki8[(size_t)row * 64 + lane] = pack4(k0, k1, k2, k3);

    const float qsc = 127.0f / qm;
    int q0 = __float2int_rn(qv.x * qsc);
    int q1 = __float2int_rn(qv.y * qsc);
    int q2 = __float2int_rn(qv.z * qsc);
    int q3 = __float2int_rn(qv.w * qsc);
    qi8[(size_t)row * 64 + lane] = pack4(q0, q1, q2, q3);

    if (lane == 0) {
        lposT[row] = qk * iq * ik * INV_T;
        fqs[row] = C1 * (0.35f / (127.0f * 127.0f)) * qm * iq;
    }
}

// ---------------- Kernel 2: int8 32x32x32 MFMA GEMM + fused exp-sum ---------
// STAGE-ONCE / SYNC-FREE COMPUTE: block = 256 Q cols x 256 K rows. The whole
// K-panel (4 tiles x 16 KB int8 = 64 KB) is staged into LDS once, then ONE
// vmcnt(0)+barrier; afterwards LDS is read-only and there is NO further sync.
// Each wave processes the 4 tiles starting at (wid + qtile) & 3 -- waves
// within a block and same-SIMD waves of the co-resident block start on
// different tiles, so one wave's exp-epilogue (VALU pipe) overlaps another's
// MFMA cluster (matrix pipe) by construction instead of colliding in
// barrier-locked phases. Traffic identical to R14 (1024 blocks x 64 KB).
// Epilogue strictly phased after cluster B (R19: interleaving spills).
// LDS: per tile [128 lrows][128 B], 16B slot s stored at s^(lrow&7).
__global__ __launch_bounds__(256, 2) void gemm_lse_kernel(
    const uint8_t* __restrict__ qi8, const uint8_t* __restrict__ ki8,
    const float* __restrict__ fqs, float* __restrict__ ps) {
    __shared__ char lds[4 * 16384];        // 64 KB -> 2 blocks/CU

    const int tid  = threadIdx.x;
    const int lane = tid & 63;
    const int wid  = tid >> 6;
    const int l31  = lane & 31;
    const int l5   = lane >> 5;

    const int qtile = blockIdx.x;              // 0..31 (x%8 -> XCD)
    const int strip = blockIdx.y;              // 0..31
    const int qw    = qtile * 256 + wid * 64;  // this wave's 64 Q cols
    const int ks0   = strip * 256;             // 256-Krow strip

    auto stage = [&](int t) {
        char* dst = lds + t * 16384;
        const int kr0 = ks0 + t * 64;
        #pragma unroll
        for (int s = 0; s < 4; ++s) {
            const int n    = wid * 4 + s;
            const int lrow = n * 8 + (lane >> 3);
            const int row  = lrow & 63;
            const int kh   = lrow >> 6;
            const uint8_t* gp = ki8 + (size_t)(kr0 + row) * 256 + kh * 128
                              + (((lane & 7) ^ (lrow & 7)) << 4);
            __builtin_amdgcn_global_load_lds(
                (const __attribute__((address_space(1))) void*)gp,
                (__attribute__((address_space(3))) void*)(dst + n * 1024),
                16, 0, 0);
        }
    };

    // ---- Q fragments + scales ----
    i32x4 qf[8][2];
    #pragma unroll
    for (int ks = 0; ks < 8; ++ks)
        #pragma unroll
        for (int cg = 0; cg < 2; ++cg)
            qf[ks][cg] = *reinterpret_cast<const i32x4*>(
                qi8 + (size_t)(qw + cg * 32 + l31) * 256 + ks * 32 + l5 * 16);
    const float f0 = fqs[qw + l31];
    const float f1 = fqs[qw + 32 + l31];

    // ---- stage the whole K-panel once ----
    stage(0); stage(1); stage(2); stage(3);
    asm volatile("s_waitcnt vmcnt(0)" ::: "memory");
    __builtin_amdgcn_s_barrier();          // the ONLY barrier; LDS read-only after

    i32x16 acc00 = {}, acc01 = {}, acc10 = {}, acc11 = {};
    float ssum0 = 0.f, ssum1 = 0.f;

    auto lda = [&](const char* src, int rg, i32x4* a) {
        const int row = rg * 32 + l31;
        #pragma unroll
        for (int ks = 0; ks < 8; ++ks) {
            const int o    = ks * 32 + l5 * 16;
            const int lrow = row + ((o >> 7) << 6);
            const int slot = ((o & 127) >> 4) ^ (lrow & 7);
            a[ks] = *reinterpret_cast<const i32x4*>(src + lrow * 128 + (slot << 4));
        }
    };

    auto expfrag = [&](i32x16& A, bool diag, float f, float& ss) {
        float s = 0.f;
        #pragma unroll
        for (int r = 0; r < 16; ++r) {
            float e = fast_exp2(fmaf((float)A[r], f, C0));
            if (diag && (((r & 3) + 8 * (r >> 2) + 4 * l5) == l31)) e = 0.f;
            s += e;
            A[r] = 0;
        }
        ss += s;
    };

    // acc01/acc10 can never contain diagonal elements (64-aligned bases,
    // row/col ranges offset by exactly 32) -> hardcoded false.
    auto epilogue = [&](int t) {
        const int kc0 = ks0 + t * 64;
        expfrag(acc00, kc0 == qw, f0, ssum0);
        expfrag(acc01, false,     f1, ssum1);
        expfrag(acc10, false,     f0, ssum0);
        expfrag(acc11, kc0 == qw, f1, ssum1);
    };

    // anti-phase start tile: decorrelates waves within the block (wid) and
    // across co-resident blocks on the same SIMD (qtile).
    const int st = (wid + qtile) & 3;

    #pragma unroll
    for (int i = 0; i < 4; ++i) {
        const int t = (st + i) & 3;
        const char* cur = lds + t * 16384;
        i32x4 a0[8], a1[8];
        lda(cur, 0, a0);
        __builtin_amdgcn_s_setprio(1);
        #pragma unroll
        for (int ks = 0; ks < 8; ++ks) {
            acc00 = __builtin_amdgcn_mfma_i32_32x32x32_i8(a0[ks], qf[ks][0], acc00, 0, 0, 0);
            acc01 = __builtin_amdgcn_mfma_i32_32x32x32_i8(a0[ks], qf[ks][1], acc01, 0, 0, 0);
        }
        __builtin_amdgcn_s_setprio(0);
        lda(cur, 1, a1);
        __builtin_amdgcn_s_setprio(1);
        #pragma unroll
        for (int ks = 0; ks < 8; ++ks) {
            acc10 = __builtin_amdgcn_mfma_i32_32x32x32_i8(a1[ks], qf[ks][0], acc10, 0, 0, 0);
            acc11 = __builtin_amdgcn_mfma_i32_32x32x32_i8(a1[ks], qf[ks][1], acc11, 0, 0, 0);
        }
        __builtin_amdgcn_s_setprio(0);
        epilogue(t);                        // strictly phased; other wave's
    }                                       // MFMAs overlap this VALU chain

    // lanes l and l^32 hold complementary row-halves of the same column
    ssum0 += __shfl_xor(ssum0, 32, 64);
    ssum1 += __shfl_xor(ssum1, 32, 64);
    if (lane < 32) {
        ps[(size_t)(qw + l31) * 32 + strip]      = ssum0;
        ps[(size_t)(qw + 32 + l31) * 32 + strip] = ssum1;
    }
}

// ---------------- Kernel 3: combine 32 strip partials -> loss ----------------
__global__ __launch_bounds__(256) void finalize_kernel(
    const float* __restrict__ ps, const float* __restrict__ lposT,
    float* __restrict__ out) {
    const int row = blockIdx.x * 256 + threadIdx.x;
    float S = 0.f;
    #pragma unroll
    for (int c = 0; c < 8; ++c) {
        const float4 p = *reinterpret_cast<const float4*>(ps + (size_t)row * 32 + c * 4);
        S += p.x + p.y + p.z + p.w;
    }
    const float lp = lposT[row];
    S += __expf(lp - M0);
    out[row] = M0 + logf(S) - lp;
}

extern "C" void kernel_launch(void* const* d_in, const int* in_sizes, int n_in,
                              void* d_out, int out_size, void* d_ws, size_t ws_size,
                              hipStream_t stream) {
    const float* q = (const float*)d_in[0];
    const float* k = (const float*)d_in[1];
    float* out = (float*)d_out;

    char* ws = (char*)d_ws;
    int*   qi8 = (int*)(ws);                                   // 2 MB
    int*   ki8 = (int*)(ws + (2u << 20));                      // 2 MB
    float* lpt = (float*)(ws + (4u << 20));                    // 32 KB
    float* fqs = (float*)(ws + (4u << 20) + (32u << 10));      // 32 KB
    float* ps  = (float*)(ws + (4u << 20) + (64u << 10));      // 1 MB

    prep_kernel<<<N_ROWS / 4, 256, 0, stream>>>(q, k, qi8, ki8, lpt, fqs);
    dim3 grid(32, 32);   // x = qtile (x%8 -> XCD), y = 256-row K strip
    gemm_lse_kernel<<<grid, 256, 0, stream>>>((const uint8_t*)qi8, (const uint8_t*)ki8, fqs, ps);
    finalize_kernel<<<N_ROWS / 256, 256, 0, stream>>>(ps, lpt, out);
}

// Round 22
// 36.868 us; speedup vs baseline: 1.0828x; 1.0828x over previous
//
#include <hip/hip_runtime.h>
#include <stdint.h>

#define N_ROWS 8192
#define DIM 256

constexpr float INV_T = 1.0f / 0.07f;
constexpr float M0    = 1.0f / 0.07f;              // fixed LSE max: |cos| <= ~1
constexpr float LOG2E = 1.44269504088896f;
constexpr float C1    = INV_T * LOG2E;             // exp2-domain scale
constexpr float C0    = -M0 * LOG2E;               // exp2-domain bias
constexpr float KSCL  = 127.0f / 0.35f;            // fixed K-side int8 scale

typedef int i32x4  __attribute__((ext_vector_type(4)));
typedef int i32x16 __attribute__((ext_vector_type(16)));

__device__ inline float fast_exp2(float x) {
    float r;
    asm("v_exp_f32 %0, %1" : "=v"(r) : "v"(x));
    return r;
}
__device__ inline int pack4(int a, int b, int c, int d) {
    return (a & 0xff) | ((b & 0xff) << 8) | ((c & 0xff) << 16) | (d << 24);
}

// ---------------- Kernel 1: normalize + int8 quantize + l_pos ----------------
__global__ __launch_bounds__(256) void prep_kernel(
    const float* __restrict__ q, const float* __restrict__ k,
    int* __restrict__ qi8, int* __restrict__ ki8,
    float* __restrict__ lposT, float* __restrict__ fqs) {
    const int wid  = threadIdx.x >> 6;
    const int lane = threadIdx.x & 63;
    const int row  = blockIdx.x * 4 + wid;

    const float4 qv = *reinterpret_cast<const float4*>(q + (size_t)row * DIM + lane * 4);
    const float4 kv = *reinterpret_cast<const float4*>(k + (size_t)row * DIM + lane * 4);

    float qq = qv.x*qv.x + qv.y*qv.y + qv.z*qv.z + qv.w*qv.w;
    float kk = kv.x*kv.x + kv.y*kv.y + kv.z*kv.z + kv.w*kv.w;
    float qk = qv.x*kv.x + qv.y*kv.y + qv.z*kv.z + qv.w*kv.w;
    float qm = fmaxf(fmaxf(fabsf(qv.x), fabsf(qv.y)), fmaxf(fabsf(qv.z), fabsf(qv.w)));

    #pragma unroll
    for (int off = 32; off > 0; off >>= 1) {
        qq += __shfl_xor(qq, off, 64);
        kk += __shfl_xor(kk, off, 64);
        qk += __shfl_xor(qk, off, 64);
        qm  = fmaxf(qm, __shfl_xor(qm, off, 64));
    }
    const float iq = 1.0f / sqrtf(qq);
    const float ik = 1.0f / sqrtf(kk);

    const float ksc = ik * KSCL;
    int k0 = __float2int_rn(fminf(fmaxf(kv.x * ksc, -127.f), 127.f));
    int k1 = __float2int_rn(fminf(fmaxf(kv.y * ksc, -127.f), 127.f));
    int k2 = __float2int_rn(fminf(fmaxf(kv.z * ksc, -127.f), 127.f));
    int k3 = __float2int_rn(fminf(fmaxf(kv.w * ksc, -127.f), 127.f));
    ki8[(size_t)row * 64 + lane] = pack4(k0, k1, k2, k3);

    const float qsc = 127.0f / qm;
    int q0 = __float2int_rn(qv.x * qsc);
    int q1 = __float2int_rn(qv.y * qsc);
    int q2 = __float2int_rn(qv.z * qsc);
    int q3 = __float2int_rn(qv.w * qsc);
    qi8[(size_t)row * 64 + lane] = pack4(q0, q1, q2, q3);

    if (lane == 0) {
        lposT[row] = qk * iq * ik * INV_T;
        fqs[row] = C1 * (0.35f / (127.0f * 127.0f)) * qm * iq;
    }
}

// ---------------- Kernel 2: int8 32x32x32 MFMA GEMM + fused exp-sum ---------
// R14 skeleton (ring-3 LDS, ONE barrier/tile, counted vmcnt(4), strictly
// phased epilogue) with ONE change: the two 16-MFMA clusters are MERGED into
// a single 32-MFMA cluster with 4-way round-robin over acc00/01/10/11.
// Rationale: with 2 interleaved chains a chain-link MFMA issues ~73 cy after
// its predecessor -- if i8 32x32x32 result latency > 73 cy every wave stalls
// on its own acc RAW hazard (matches 21 rounds of scheduling nulls pinned at
// MfmaUtil~29% ~= 36.6/128). 4-way round-robin gives ~146 cy between
// same-chain MFMAs. a0/a1 co-live (peak ~240 VGPR, no spill expected).
// LDS: [128 lrows][128 B], 16B slot s stored at s^(lrow&7) (zero-conflict).
__global__ __launch_bounds__(256, 2) void gemm_lse_kernel(
    const uint8_t* __restrict__ qi8, const uint8_t* __restrict__ ki8,
    const float* __restrict__ fqs, float* __restrict__ ps) {
    __shared__ char lds[3 * 16384];

    const int tid  = threadIdx.x;
    const int lane = tid & 63;
    const int wid  = tid >> 6;
    const int l31  = lane & 31;
    const int l5   = lane >> 5;

    const int qtile = blockIdx.x;              // 0..31 (x%8 -> XCD)
    const int strip = blockIdx.y;              // 0..15
    const int qw    = qtile * 256 + wid * 64;  // this wave's 64 Q cols
    const int ks0   = strip * 512;

    auto stage = [&](int t) {
        char* dst = lds + (t % 3) * 16384;
        const int kr0 = ks0 + t * 64;
        #pragma unroll
        for (int s = 0; s < 4; ++s) {
            const int n    = wid * 4 + s;
            const int lrow = n * 8 + (lane >> 3);
            const int row  = lrow & 63;
            const int kh   = lrow >> 6;
            const uint8_t* gp = ki8 + (size_t)(kr0 + row) * 256 + kh * 128
                              + (((lane & 7) ^ (lrow & 7)) << 4);
            __builtin_amdgcn_global_load_lds(
                (const __attribute__((address_space(1))) void*)gp,
                (__attribute__((address_space(3))) void*)(dst + n * 1024),
                16, 0, 0);
        }
    };

    // ---- Q fragments + scales FIRST (oldest in vmcnt order) ----
    i32x4 qf[8][2];
    #pragma unroll
    for (int ks = 0; ks < 8; ++ks)
        #pragma unroll
        for (int cg = 0; cg < 2; ++cg)
            qf[ks][cg] = *reinterpret_cast<const i32x4*>(
                qi8 + (size_t)(qw + cg * 32 + l31) * 256 + ks * 32 + l5 * 16);
    const float f0 = fqs[qw + l31];
    const float f1 = fqs[qw + 32 + l31];

    stage(0);
    stage(1);

    i32x16 acc00 = {}, acc01 = {}, acc10 = {}, acc11 = {};
    float ssum0 = 0.f, ssum1 = 0.f;

    auto lda = [&](const char* src, int rg, i32x4* a) {
        const int row = rg * 32 + l31;
        #pragma unroll
        for (int ks = 0; ks < 8; ++ks) {
            const int o    = ks * 32 + l5 * 16;
            const int lrow = row + ((o >> 7) << 6);
            const int slot = ((o & 127) >> 4) ^ (lrow & 7);
            a[ks] = *reinterpret_cast<const i32x4*>(src + lrow * 128 + (slot << 4));
        }
    };

    auto expfrag = [&](i32x16& A, bool diag, float f, float& ss) {
        float s = 0.f;
        #pragma unroll
        for (int r = 0; r < 16; ++r) {
            float e = fast_exp2(fmaf((float)A[r], f, C0));
            if (diag && (((r & 3) + 8 * (r >> 2) + 4 * l5) == l31)) e = 0.f;
            s += e;
            A[r] = 0;
        }
        ss += s;
    };

    // acc01/acc10 can never contain diagonal elements (kc0, qw both 64-aligned;
    // their row/col ranges are offset by exactly 32) -> hardcoded false.
    auto epilogue = [&](int t) {
        const int kc0 = ks0 + t * 64;
        expfrag(acc00, kc0 == qw, f0, ssum0);
        expfrag(acc01, false,     f1, ssum1);
        expfrag(acc10, false,     f0, ssum0);
        expfrag(acc11, kc0 == qw, f1, ssum1);
    };

    #pragma unroll
    for (int t = 0; t < 8; ++t) {
        if (t < 7) { asm volatile("s_waitcnt vmcnt(4)" ::: "memory"); }  // tile t landed (mine)
        else       { asm volatile("s_waitcnt vmcnt(0)" ::: "memory"); }
        __builtin_amdgcn_s_barrier();          // everyone's tile t in LDS; compute(t-1) done
        __builtin_amdgcn_sched_barrier(0);
        if (t < 6) stage(t + 2);               // overwrites buf[(t-1)%3] -- safe post-barrier
        if (t > 0) epilogue(t - 1);            // reg-only, fills the stage/lda window

        const char* cur = lds + (t % 3) * 16384;
        i32x4 a0[8], a1[8];
        lda(cur, 0, a0);
        lda(cur, 1, a1);
        __builtin_amdgcn_s_setprio(1);
        #pragma unroll
        for (int ks = 0; ks < 8; ++ks) {       // 4-way round-robin: same-chain
            acc00 = __builtin_amdgcn_mfma_i32_32x32x32_i8(a0[ks], qf[ks][0], acc00, 0, 0, 0);
            acc01 = __builtin_amdgcn_mfma_i32_32x32x32_i8(a0[ks], qf[ks][1], acc01, 0, 0, 0);
            acc10 = __builtin_amdgcn_mfma_i32_32x32x32_i8(a1[ks], qf[ks][0], acc10, 0, 0, 0);
            acc11 = __builtin_amdgcn_mfma_i32_32x32x32_i8(a1[ks], qf[ks][1], acc11, 0, 0, 0);
        }                                      // MFMAs now ~146 cy apart
        __builtin_amdgcn_s_setprio(0);
    }
    epilogue(7);

    // lanes l and l^32 hold complementary row-halves of the same column
    ssum0 += __shfl_xor(ssum0, 32, 64);
    ssum1 += __shfl_xor(ssum1, 32, 64);
    if (lane < 32) {
        ps[(size_t)(qw + l31) * 16 + strip]      = ssum0;
        ps[(size_t)(qw + 32 + l31) * 16 + strip] = ssum1;
    }
}

// ---------------- Kernel 3: combine 16 strip partials -> loss ----------------
__global__ __launch_bounds__(256) void finalize_kernel(
    const float* __restrict__ ps, const float* __restrict__ lposT,
    float* __restrict__ out) {
    const int row = blockIdx.x * 256 + threadIdx.x;
    float S = 0.f;
    #pragma unroll
    for (int c = 0; c < 4; ++c) {
        const float4 p = *reinterpret_cast<const float4*>(ps + (size_t)row * 16 + c * 4);
        S += p.x + p.y + p.z + p.w;
    }
    const float lp = lposT[row];
    S += __expf(lp - M0);
    out[row] = M0 + logf(S) - lp;
}

extern "C" void kernel_launch(void* const* d_in, const int* in_sizes, int n_in,
                              void* d_out, int out_size, void* d_ws, size_t ws_size,
                              hipStream_t stream) {
    const float* q = (const float*)d_in[0];
    const float* k = (const float*)d_in[1];
    float* out = (float*)d_out;

    char* ws = (char*)d_ws;
    int*   qi8 = (int*)(ws);                                   // 2 MB
    int*   ki8 = (int*)(ws + (2u << 20));                      // 2 MB
    float* lpt = (float*)(ws + (4u << 20));                    // 32 KB
    float* fqs = (float*)(ws + (4u << 20) + (32u << 10));      // 32 KB
    float* ps  = (float*)(ws + (4u << 20) + (64u << 10));      // 512 KB

    prep_kernel<<<N_ROWS / 4, 256, 0, stream>>>(q, k, qi8, ki8, lpt, fqs);
    dim3 grid(32, 16);   // x = qtile (x%8 -> XCD), y = strip
    gemm_lse_kernel<<<grid, 256, 0, stream>>>((const uint8_t*)qi8, (const uint8_t*)ki8, fqs, ps);
    finalize_kernel<<<N_ROWS / 256, 256, 0, stream>>>(ps, lpt, out);
}